// Round 5
// baseline (81.676 us; speedup 1.0000x reference)
//
#include <hip/hip_runtime.h>
#include <math.h>

#define Bq 32
#define Nq 1024
#define BPR 16            // blocks per row
#define TPB 256
#define NBLK (BPR * Bq)

// ws layout: float acc[2*Bq]; int done[1];  -> zeroed via hipMemsetAsync (260 B)

__global__ __launch_bounds__(TPB)
void fused_kernel(const float* __restrict__ yp,
                  const float* __restrict__ yt,
                  const int* __restrict__ masks,
                  float* __restrict__ acc,
                  int* __restrict__ done,
                  float* __restrict__ out) {
    const int row = blockIdx.y;
    const int tid = threadIdx.x;
    const int lane = tid & 63;
    const int wid = tid >> 6;        // 4 waves

    __shared__ float4 sv[Nq];        // compacted (pred, true, disc, -) 16 KB
    __shared__ int wsum[4];
    __shared__ float rl[4], rc[4];

    // ---- per-block prep: scan mask row, compact valid items into LDS ----
    const int b0 = tid * 4;          // contiguous 4-element segment per thread
    int m0 = masks[row * Nq + b0 + 0] > 0;
    int m1 = masks[row * Nq + b0 + 1] > 0;
    int m2 = masks[row * Nq + b0 + 2] > 0;
    int m3 = masks[row * Nq + b0 + 3] > 0;
    const int tot = m0 + m1 + m2 + m3;

    // wave inclusive scan of per-thread totals
    int val = tot;
#pragma unroll
    for (int off = 1; off < 64; off <<= 1) {
        int n = __shfl_up(val, off, 64);
        if (lane >= off) val += n;
    }
    if (lane == 63) wsum[wid] = val;
    __syncthreads();

    int wbase = 0;
#pragma unroll
    for (int w = 0; w < 4; ++w) wbase += (w < wid) ? wsum[w] : 0;
    const int V = wsum[0] + wsum[1] + wsum[2] + wsum[3];
    int rank = wbase + val - tot;    // 0-indexed rank of first valid elem in my segment

    {
        int mm[4] = {m0, m1, m2, m3};
#pragma unroll
        for (int k = 0; k < 4; ++k) {
            if (mm[k]) {
                const float d = 1.0f / log2f((float)rank + 2.0f);
                sv[rank] = make_float4(yp[row * Nq + b0 + k], yt[row * Nq + b0 + k], d, 0.0f);
                ++rank;
            }
        }
    }
    __syncthreads();

    // ---- triangular pair loop over compacted items ----
    const int P = V * (V - 1) / 2;
    const int T = NBLK / Bq * TPB;               // threads per row = BPR*TPB
    const int tgl = blockIdx.x * TPB + tid;
    const int chunk = (P + T - 1) / T;
    const int k0 = tgl * chunk;
    const int k1 = min(k0 + chunk, P);

    float loss = 0.0f;
    float cnt = 0.0f;

    if (k0 < k1) {
        int i = (int)((1.0 + sqrt(1.0 + 8.0 * (double)k0)) * 0.5);
        if (i < 1) i = 1;
        while (i * (i - 1) / 2 > k0) --i;
        while ((i + 1) * i / 2 <= k0) ++i;
        int j = k0 - i * (i - 1) / 2;

        float4 qi = sv[i];
#pragma unroll 1
        for (int k = k0; k < k1; ++k) {
            const float4 qj = sv[j];
            const bool win = qi.y > qj.y;
            const float x = win ? (qj.x - qi.x) : (qi.x - qj.x);   // pred_loser - pred_winner
            const float a = __expf(-fabsf(x));
            const float spv = fmaxf(x, 0.0f) + __logf(1.0f + a);   // stable softplus
            const bool ok = (qi.y != qj.y);
            const float w = ok ? (qi.z + qj.z) : 0.0f;
            loss = fmaf(spv, w, loss);
            cnt += ok ? 1.0f : 0.0f;
            if (++j == i) { j = 0; ++i; if (i < V) qi = sv[i]; }
        }
    }

    // ---- block reduction ----
#pragma unroll
    for (int off = 32; off > 0; off >>= 1) {
        loss += __shfl_down(loss, off, 64);
        cnt  += __shfl_down(cnt, off, 64);
    }
    if (lane == 0) { rl[wid] = loss; rc[wid] = cnt; }
    __syncthreads();

    if (tid == 0) {
        const float L = rl[0] + rl[1] + rl[2] + rl[3];
        const float C = rc[0] + rc[1] + rc[2] + rc[3];
        atomicAdd(&acc[2 * row + 0], L);
        atomicAdd(&acc[2 * row + 1], C);
        __threadfence();
        const int old = __hip_atomic_fetch_add(done, 1, __ATOMIC_ACQ_REL, __HIP_MEMORY_SCOPE_AGENT);
        if (old == NBLK - 1) {
            float s = 0.0f;
            for (int r = 0; r < Bq; ++r) {
                const float L2 = __hip_atomic_load(&acc[2 * r + 0], __ATOMIC_RELAXED, __HIP_MEMORY_SCOPE_AGENT);
                const float C2 = __hip_atomic_load(&acc[2 * r + 1], __ATOMIC_RELAXED, __HIP_MEMORY_SCOPE_AGENT);
                s += L2 / (C2 + 1e-12f);
            }
            out[0] = s / (float)Bq;
        }
    }
}

extern "C" void kernel_launch(void* const* d_in, const int* in_sizes, int n_in,
                              void* d_out, int out_size, void* d_ws, size_t ws_size,
                              hipStream_t stream) {
    const float* y_pred = (const float*)d_in[0];
    const float* y_true = (const float*)d_in[1];
    const int*   masks  = (const int*)d_in[2];
    float* out = (float*)d_out;

    float* acc  = (float*)d_ws;                 // 64 floats
    int*   done = (int*)(acc + 2 * Bq);         // 1 int

    hipMemsetAsync(d_ws, 0, 2 * Bq * sizeof(float) + sizeof(int), stream);
    fused_kernel<<<dim3(BPR, Bq), TPB, 0, stream>>>(y_pred, y_true, masks, acc, done, out);
}